// Round 9
// baseline (128.476 us; speedup 1.0000x reference)
//
#include <hip/hip_runtime.h>
#include <hip/hip_cooperative_groups.h>

// S=32 systems, N=512 atoms/system, F=256 features
#define SY 32
#define NA 512
#define FD 256

typedef __attribute__((ext_vector_type(8))) short bf16x8;   // 8 bf16 = 4 VGPRs
typedef __attribute__((ext_vector_type(4))) short bf16x4;   // 4 bf16 = 8 B
typedef __attribute__((ext_vector_type(4))) float f32x4;    // MFMA C/D frag

static __device__ __forceinline__ short f2bf(float x) {
    union { float f; unsigned u; } v; v.f = x;
    unsigned r = v.u + 0x7fffu + ((v.u >> 16) & 1u);   // RNE
    return (short)(r >> 16);
}
static __device__ __forceinline__ float bf2f(short x) {
    union { float f; unsigned u; } v;
    v.u = ((unsigned)(unsigned short)x) << 16;
    return v.f;
}

// ---------------------------------------------------------------------------
// prep: W fp32 -> bf16 (row-major [f][k] unchanged). 64 blocks x 256 thr.
// ---------------------------------------------------------------------------
__global__ __launch_bounds__(256) void prep_w(
    const float* __restrict__ W, short* __restrict__ Wb)
{
    int idx = (blockIdx.x * 256 + threadIdx.x) * 4;   // 65536 elems total
    float4 v = *(const float4*)&W[idx];
    bf16x4 p; p[0] = f2bf(v.x); p[1] = f2bf(v.y);
              p[2] = f2bf(v.z); p[3] = f2bf(v.w);
    *(bf16x4*)&Wb[idx] = p;
}

// ---------------------------------------------------------------------------
// Kernel 1 v3: charges = features @ W^T + b via bf16 MFMA (fp32 accum).
// 512 blocks x 256 thr, 32 i-rows x 256 f each; LDS 41.5 KB.
// Wave w owns f in [64w, 64w+64). Wb (bf16) staged raw; feat cvt in-kernel.
// qT (bf16 [s][f][j]) written via LDS transpose reusing sB.
// Fallback: Wb==nullptr -> stage W fp32; qfp!=nullptr -> also write fp32 q.
// ---------------------------------------------------------------------------
__global__ __launch_bounds__(256) void charges_v3(
    const float* __restrict__ feat, const float* __restrict__ Wfp,
    const short* __restrict__ Wb, const float* __restrict__ b,
    float* __restrict__ qfp, short* __restrict__ qT)
{
    __shared__ __attribute__((aligned(16))) short sA[32 * 72];   //  4.6 KB
    __shared__ __attribute__((aligned(16))) short sB[256 * 72];  // 36.9 KB
    const int t    = threadIdx.x;
    const int i0   = blockIdx.x * 32;
    const int w    = t >> 6;
    const int lane = t & 63;
    const int n16  = lane & 15;
    const int quad = lane >> 4;

    f32x4 acc[2][4];
    #pragma unroll
    for (int a = 0; a < 2; ++a)
        #pragma unroll
        for (int c = 0; c < 4; ++c) acc[a][c] = (f32x4)0.0f;

    for (int k0 = 0; k0 < FD; k0 += 64) {
        // stage feat tile 32i x 64k (2 float4/thread, cvt to bf16)
        #pragma unroll
        for (int m = 0; m < 2; ++m) {
            int lin = t + 256 * m;            // 0..511
            int row = lin >> 4, kq = lin & 15;
            float4 v = *(const float4*)&feat[(size_t)(i0 + row) * FD + k0 + 4 * kq];
            bf16x4 p; p[0] = f2bf(v.x); p[1] = f2bf(v.y);
                      p[2] = f2bf(v.z); p[3] = f2bf(v.w);
            *(bf16x4*)&sA[row * 72 + 4 * kq] = p;
        }
        // stage W tile 256f x 64k
        if (Wb) {
            #pragma unroll
            for (int n = 0; n < 8; ++n) {
                int S = t + 256 * n;          // 0..2047
                int f = S >> 3, c = S & 7;
                uint4 v = *(const uint4*)&Wb[(size_t)f * FD + k0 + c * 8];
                *(uint4*)&sB[f * 72 + c * 8] = v;
            }
        } else {
            #pragma unroll
            for (int m = 0; m < 16; ++m) {
                int lin = t + 256 * m;        // 0..4095
                int f = lin >> 4, kq = lin & 15;
                float4 v = *(const float4*)&Wfp[(size_t)f * FD + k0 + 4 * kq];
                bf16x4 p; p[0] = f2bf(v.x); p[1] = f2bf(v.y);
                          p[2] = f2bf(v.z); p[3] = f2bf(v.w);
                *(bf16x4*)&sB[f * 72 + 4 * kq] = p;
            }
        }
        __syncthreads();

        #pragma unroll
        for (int ks = 0; ks < 64; ks += 32) {
            bf16x8 af[2], bfr[4];
            #pragma unroll
            for (int it = 0; it < 2; ++it)
                af[it] = *(const bf16x8*)&sA[(16 * it + n16) * 72 + ks + quad * 8];
            #pragma unroll
            for (int fb = 0; fb < 4; ++fb)
                bfr[fb] = *(const bf16x8*)&sB[(64 * w + 16 * fb + n16) * 72 + ks + quad * 8];
            #pragma unroll
            for (int it = 0; it < 2; ++it)
                #pragma unroll
                for (int fb = 0; fb < 4; ++fb)
                    acc[it][fb] = __builtin_amdgcn_mfma_f32_16x16x32_bf16(
                        af[it], bfr[fb], acc[it][fb], 0, 0, 0);
        }
        __syncthreads();
    }

    float bias[4];
    #pragma unroll
    for (int fb = 0; fb < 4; ++fb) bias[fb] = b[64 * w + 16 * fb + n16];

    if (qfp) {   // fallback path needs fp32 q
        #pragma unroll
        for (int it = 0; it < 2; ++it)
            #pragma unroll
            for (int fb = 0; fb < 4; ++fb)
                #pragma unroll
                for (int r = 0; r < 4; ++r) {
                    int i = i0 + 16 * it + 4 * quad + r;
                    int f = 64 * w + 16 * fb + n16;
                    qfp[(size_t)i * FD + f] = acc[it][fb][r] + bias[fb];
                }
    }

    if (qT) {
        // transpose via sB reuse (pitch 40 shorts), then coalesced stores
        short* tr = sB;
        #pragma unroll
        for (int it = 0; it < 2; ++it)
            #pragma unroll
            for (int fb = 0; fb < 4; ++fb) {
                bf16x4 p;
                #pragma unroll
                for (int r = 0; r < 4; ++r) p[r] = f2bf(acc[it][fb][r] + bias[fb]);
                int f = 64 * w + 16 * fb + n16;
                *(bf16x4*)&tr[f * 40 + 16 * it + 4 * quad] = p;
            }
        __syncthreads();
        short* qTs = qT + ((size_t)(i0 >> 9)) * FD * NA;
        const int ilb = i0 & 511;
        #pragma unroll
        for (int n = 0; n < 4; ++n) {
            int S = t + 256 * n;          // 0..1023
            int f = S >> 2, c = S & 3;
            uint4 v = *(const uint4*)&tr[f * 40 + c * 8];
            *(uint4*)&qTs[(size_t)f * NA + ilb + c * 8] = v;
        }
    }
}

// ---------------------------------------------------------------------------
// Kernel 2 FAST v4: V = 0.5 * v @ q (bf16 MFMA), out = V * q (pure store).
// R9: revert to R6's block shape — grid 512 (s = blk&31 XCD-local, 32 i-rows,
// FULL 256-f tile, 16 mfma/wave/iter), which beat the R7/R8 f-split.
// Spill fixes kept: qreg loaded from qT AFTER the j-loop (epilogue-only live
// range; R7 in-loop-conditional and R8 before-loop both spilled to scratch);
// launch_bounds(256,2) -> VGPR budget 256 so acc+pf stay in registers.
// LDS 42 KB -> 3 blocks/CU.
// ---------------------------------------------------------------------------
__global__ __launch_bounds__(256, 2) void lr_fast(
    const float* __restrict__ pos, float* __restrict__ out,
    const short* __restrict__ qT)
{
    __shared__ float px[NA], py[NA], pz[NA];
    __shared__ __attribute__((aligned(16))) short sqb[FD * 64];   // 32 KB
    __shared__ __attribute__((aligned(16))) short svb[32 * 64];   //  4 KB

    const int blk = blockIdx.x;
    const int s   = blk & 31;
    const int i0  = (blk >> 5) * 32;
    const int t   = threadIdx.x;
    const int w    = t >> 6;
    const int lane = t & 63;
    const int n16  = lane & 15;
    const int quad = lane >> 4;

    for (int m = t; m < NA; m += 256) {
        const float* p = &pos[((size_t)s * NA + m) * 3];
        px[m] = p[0]; py[m] = p[1]; pz[m] = p[2];
    }

    f32x4 acc[2][4];
    #pragma unroll
    for (int a = 0; a < 2; ++a)
        #pragma unroll
        for (int c = 0; c < 4; ++c) acc[a][c] = (f32x4)0.0f;

    const short* qTs = qT + (size_t)s * FD * NA;
    const int pi = t & 31;        // pair-tile i
    const int pc = t >> 5;        // pair-tile j-chunk 0..7
    const int gi = i0 + pi;

    // prefetch first q tile (8 x 16B chunks per thread = 256f x 64j)
    uint4 pf[8];
    #pragma unroll
    for (int n = 0; n < 8; ++n) {
        int S  = t + 256 * n;         // 0..2047
        int fl = S >> 3;
        int cs = S & 7;
        int c  = (cs - fl) & 7;
        pf[n] = *(const uint4*)&qTs[(size_t)fl * NA + 0 + c * 8];
    }

    __syncthreads();
    const float xi = px[gi], yi = py[gi], zi = pz[gi];

    for (int j0 = 0; j0 < NA; j0 += 64) {
        // ---- commit prefetched q tile to LDS ----
        #pragma unroll
        for (int n = 0; n < 8; ++n) {
            int S  = t + 256 * n;
            int fl = S >> 3;
            int cs = S & 7;
            *(uint4*)&sqb[fl * 64 + cs * 8] = pf[n];
        }
        // ---- v tile: 32i x 64j ----
        bf16x8 vrow;
        #pragma unroll
        for (int jj = 0; jj < 8; ++jj) {
            int gj = j0 + pc * 8 + jj;
            float dx = xi - px[gj];
            float dy = yi - py[gj];
            float dz = zi - pz[gj];
            float r2 = dx * dx + dy * dy + dz * dz;
            float inv = __builtin_amdgcn_rsqf(r2);
            float dd  = r2 * inv;
            // 1 - fcut = sin^2(pi*d/10) for d<5, else 1; 0.5 energy factor
            float sn = __sinf(dd * 0.31415926535f);
            float om = (dd < 5.0f) ? sn * sn : 1.0f;
            float vv = (gi != gj) ? 0.5f * om * inv : 0.0f;
            vrow[jj] = f2bf(vv);
        }
        *(bf16x8*)&svb[pi * 64 + (((pc + pi) & 7) * 8)] = vrow;
        // ---- issue next tile's loads (consumed next iteration) ----
        {
            int jn = (j0 + 64) & (NA - 1);
            #pragma unroll
            for (int n = 0; n < 8; ++n) {
                int S  = t + 256 * n;
                int fl = S >> 3;
                int cs = S & 7;
                int c  = (cs - fl) & 7;
                pf[n] = *(const uint4*)&qTs[(size_t)fl * NA + jn + c * 8];
            }
        }
        __syncthreads();

        // ---- fragments + MFMA: 2 it x 4 fb x 2 kh = 16 mfma / wave ----
        bf16x8 af[2][2], bfr[2][4];
        #pragma unroll
        for (int it = 0; it < 2; ++it)
            #pragma unroll
            for (int kh = 0; kh < 2; ++kh) {
                int i = 16 * it + n16;
                int c = kh * 4 + quad;
                af[it][kh] = *(const bf16x8*)&svb[i * 64 + (((c + i) & 7) * 8)];
            }
        #pragma unroll
        for (int fb = 0; fb < 4; ++fb)
            #pragma unroll
            for (int kh = 0; kh < 2; ++kh) {
                int fl = 64 * w + 16 * fb + n16;
                int c  = kh * 4 + quad;
                bfr[kh][fb] = *(const bf16x8*)&sqb[fl * 64 + (((c + fl) & 7) * 8)];
            }
        #pragma unroll
        for (int kh = 0; kh < 2; ++kh)
            #pragma unroll
            for (int it = 0; it < 2; ++it)
                #pragma unroll
                for (int fb = 0; fb < 4; ++fb)
                    acc[it][fb] = __builtin_amdgcn_mfma_f32_16x16x32_bf16(
                        af[it][kh], bfr[kh][fb], acc[it][fb], 0, 0, 0);
        __syncthreads();
    }

    // epilogue: load own q from qT NOW (short live range), out = V * q
    #pragma unroll
    for (int it = 0; it < 2; ++it)
        #pragma unroll
        for (int fb = 0; fb < 4; ++fb) {
            int fl = 64 * w + 16 * fb + n16;
            bf16x4 p = *(const bf16x4*)&qTs[(size_t)fl * NA + i0 + 16 * it + 4 * quad];
            #pragma unroll
            for (int r = 0; r < 4; ++r) {
                int i = i0 + 16 * it + 4 * quad + r;
                size_t a = ((size_t)s * NA + i) * FD + fl;
                out[a] = acc[it][fb][r] * bf2f(p[r]);
            }
        }
}

// ---------------------------------------------------------------------------
// Kernel 2 FALLBACK (cooperative, validated round 4) — used if ws too small.
// ---------------------------------------------------------------------------
__global__ __launch_bounds__(256) void lr_coop(
    const float* __restrict__ pos, float* __restrict__ gbuf)
{
    __shared__ float px[NA], py[NA], pz[NA];
    __shared__ __attribute__((aligned(16))) short svb[64 * 40];
    __shared__ __attribute__((aligned(16))) short sqb[FD * 40];

    const int blk = blockIdx.x;
    const int s   = blk & 31;
    const int i0  = (blk >> 5) * 64;
    const int t   = threadIdx.x;
    const int w    = t >> 6;
    const int lane = t & 63;
    const int n16  = lane & 15;
    const int quad = lane >> 4;

    for (int m = t; m < NA; m += 256) {
        const float* p = &pos[((size_t)s * NA + m) * 3];
        px[m] = p[0]; py[m] = p[1]; pz[m] = p[2];
    }

    f32x4 acc[4][4];
    #pragma unroll
    for (int a = 0; a < 4; ++a)
        #pragma unroll
        for (int c = 0; c < 4; ++c) acc[a][c] = (f32x4)0.0f;

    __syncthreads();

    const int fq  = t >> 2;
    const int jb  = t & 3;
    const int iv  = t & 63;
    const int jbv = t >> 6;
    const int gi  = i0 + iv;

    float4 rq[8];
    #pragma unroll
    for (int m = 0; m < 8; ++m)
        rq[m] = *(const float4*)&gbuf[((size_t)s * NA + 8 * jb + m) * FD + 4 * fq];

    for (int j0 = 0; j0 < NA; j0 += 32) {
        bf16x8 vrow;
        #pragma unroll
        for (int jj = 0; jj < 8; ++jj) {
            int gj = j0 + 8 * jbv + jj;
            float dx = px[gi] - px[gj];
            float dy = py[gi] - py[gj];
            float dz = pz[gi] - pz[gj];
            float dd = sqrtf(dx * dx + dy * dy + dz * dz);
            float om = (dd < 5.0f) ? 0.5f * (1.0f - __cosf(dd * 0.62831853071795f))
                                   : 1.0f;
            float vv = (gi != gj) ? (0.5f * om * __builtin_amdgcn_rcpf(dd)) : 0.0f;
            vrow[jj] = f2bf(vv);
        }
        bf16x8 rows[4];
        #pragma unroll
        for (int m = 0; m < 8; ++m) {
            rows[0][m] = f2bf(rq[m].x);
            rows[1][m] = f2bf(rq[m].y);
            rows[2][m] = f2bf(rq[m].z);
            rows[3][m] = f2bf(rq[m].w);
        }
        #pragma unroll
        for (int d = 0; d < 4; ++d) {
            int f = 4 * fq + d;
            int phys = (jb + (f >> 3)) & 3;
            *(bf16x8*)&sqb[f * 40 + phys * 8] = rows[d];
        }
        {
            int phys = (jbv + (iv >> 3)) & 3;
            *(bf16x8*)&svb[iv * 40 + phys * 8] = vrow;
        }
        {
            int jn = (j0 + 32) & (NA - 1);
            #pragma unroll
            for (int m = 0; m < 8; ++m)
                rq[m] = *(const float4*)&gbuf[((size_t)s * NA + jn + 8 * jb + m) * FD + 4 * fq];
        }
        __syncthreads();

        bf16x8 af[4], bfr[4];
        #pragma unroll
        for (int it = 0; it < 4; ++it) {
            int i = 16 * it + n16;
            int phys = (quad + (i >> 3)) & 3;
            af[it] = *(const bf16x8*)&svb[i * 40 + phys * 8];
        }
        #pragma unroll
        for (int fb = 0; fb < 4; ++fb) {
            int f = 16 * (4 * w + fb) + n16;
            int phys = (quad + (f >> 3)) & 3;
            bfr[fb] = *(const bf16x8*)&sqb[f * 40 + phys * 8];
        }
        #pragma unroll
        for (int it = 0; it < 4; ++it)
            #pragma unroll
            for (int fb = 0; fb < 4; ++fb)
                acc[it][fb] = __builtin_amdgcn_mfma_f32_16x16x32_bf16(
                    af[it], bfr[fb], acc[it][fb], 0, 0, 0);
        __syncthreads();
    }

    cooperative_groups::this_grid().sync();

    #pragma unroll
    for (int it = 0; it < 4; ++it)
        #pragma unroll
        for (int fb = 0; fb < 4; ++fb)
            #pragma unroll
            for (int r = 0; r < 4; ++r) {
                int i = i0 + 16 * it + 4 * quad + r;
                int f = 16 * (4 * w + fb) + n16;
                size_t a = ((size_t)s * NA + i) * FD + f;
                gbuf[a] = acc[it][fb][r] * gbuf[a];
            }
}

extern "C" void kernel_launch(void* const* d_in, const int* in_sizes, int n_in,
                              void* d_out, int out_size, void* d_ws, size_t ws_size,
                              hipStream_t stream) {
    const float* positions = (const float*)d_in[0];  // [32,512,3]
    const float* features  = (const float*)d_in[1];  // [16384,256]
    const float* W         = (const float*)d_in[2];  // [256,256]
    const float* b         = (const float*)d_in[3];  // [256]
    float* gbuf = (float*)d_out;

    const size_t qT_elems = (size_t)SY * NA * FD;          // 4M bf16
    const size_t need = (qT_elems + FD * FD) * sizeof(short);  // 8 MB + 128 KB
    const bool fast = (ws_size >= need);

    if (fast) {
        short* qT = (short*)d_ws;
        short* Wb = (short*)d_ws + qT_elems;
        prep_w<<<dim3(64), 256, 0, stream>>>(W, Wb);
        charges_v3<<<dim3(512), 256, 0, stream>>>(features, W, Wb, b, nullptr, qT);
        lr_fast<<<dim3(512), 256, 0, stream>>>(positions, gbuf, qT);
    } else {
        charges_v3<<<dim3(512), 256, 0, stream>>>(features, W, nullptr, b, gbuf, nullptr);
        void* args[] = {(void*)&positions, (void*)&gbuf};
        hipLaunchCooperativeKernel((void*)lr_coop, dim3(256), dim3(256),
                                   args, 0, stream);
    }
}

// Round 10
// 112.794 us; speedup vs baseline: 1.1390x; 1.1390x over previous
//
#include <hip/hip_runtime.h>
#include <hip/hip_cooperative_groups.h>

// S=32 systems, N=512 atoms/system, F=256 features
#define SY 32
#define NA 512
#define FD 256

typedef __attribute__((ext_vector_type(8))) short bf16x8;   // 8 bf16 = 4 VGPRs
typedef __attribute__((ext_vector_type(4))) short bf16x4;   // 4 bf16 = 8 B
typedef __attribute__((ext_vector_type(4))) float f32x4;    // MFMA C/D frag

static __device__ __forceinline__ short f2bf(float x) {
    union { float f; unsigned u; } v; v.f = x;
    unsigned r = v.u + 0x7fffu + ((v.u >> 16) & 1u);   // RNE
    return (short)(r >> 16);
}
static __device__ __forceinline__ float bf2f(short x) {
    union { float f; unsigned u; } v;
    v.u = ((unsigned)(unsigned short)x) << 16;
    return v.f;
}

// ---------------------------------------------------------------------------
// prep: W fp32 -> bf16 (row-major [f][k] unchanged). 64 blocks x 256 thr.
// ---------------------------------------------------------------------------
__global__ __launch_bounds__(256) void prep_w(
    const float* __restrict__ W, short* __restrict__ Wb)
{
    int idx = (blockIdx.x * 256 + threadIdx.x) * 4;   // 65536 elems total
    float4 v = *(const float4*)&W[idx];
    bf16x4 p; p[0] = f2bf(v.x); p[1] = f2bf(v.y);
              p[2] = f2bf(v.z); p[3] = f2bf(v.w);
    *(bf16x4*)&Wb[idx] = p;
}

// ---------------------------------------------------------------------------
// Kernel 1 v2.5: charges = features @ W^T + b via bf16 MFMA (fp32 accum).
// R6's validated 512-thread shape (256 blocks x 64 i-rows, wave w owns
// f in [32w,32w+32)) with two local changes vs R6:
//   (a) W staged pre-converted bf16 (Wb) -> raw uint4 copies, no cvt VALU;
//   (b) qT transpose reuses sB (was a 3rd 37KB buffer) -> LDS 83->46 KB,
//       3 blocks/CU instead of 1.
// Fallback: Wb==nullptr -> stage W fp32; qfp!=nullptr -> also write fp32 q.
// ---------------------------------------------------------------------------
__global__ __launch_bounds__(512) void charges_v25(
    const float* __restrict__ feat, const float* __restrict__ Wfp,
    const short* __restrict__ Wb, const float* __restrict__ b,
    float* __restrict__ qfp, short* __restrict__ qT)
{
    __shared__ __attribute__((aligned(16))) short sA[64 * 72];   //  9.2 KB
    __shared__ __attribute__((aligned(16))) short sB[256 * 72];  // 36.9 KB
    const int t    = threadIdx.x;
    const int i0   = blockIdx.x * 64;
    const int w    = t >> 6;            // wave 0..7
    const int lane = t & 63;
    const int n16  = lane & 15;
    const int quad = lane >> 4;

    f32x4 acc[4][2];
    #pragma unroll
    for (int a = 0; a < 4; ++a)
        #pragma unroll
        for (int c = 0; c < 2; ++c) acc[a][c] = (f32x4)0.0f;

    for (int k0 = 0; k0 < FD; k0 += 64) {
        // stage feat tile 64i x 64k (2 float4/thread, cvt to bf16)
        #pragma unroll
        for (int m = 0; m < 2; ++m) {
            int lin = t + 512 * m;            // 0..1023
            int row = lin >> 4, kq = lin & 15;
            float4 v = *(const float4*)&feat[(size_t)(i0 + row) * FD + k0 + 4 * kq];
            bf16x4 p; p[0] = f2bf(v.x); p[1] = f2bf(v.y);
                      p[2] = f2bf(v.z); p[3] = f2bf(v.w);
            *(bf16x4*)&sA[row * 72 + 4 * kq] = p;
        }
        // stage W tile 256f x 64k
        if (Wb) {
            #pragma unroll
            for (int n = 0; n < 4; ++n) {
                int S = t + 512 * n;          // 0..2047 16B chunks
                int f = S >> 3, c = S & 7;
                uint4 v = *(const uint4*)&Wb[(size_t)f * FD + k0 + c * 8];
                *(uint4*)&sB[f * 72 + c * 8] = v;
            }
        } else {
            #pragma unroll
            for (int m = 0; m < 8; ++m) {
                int lin = t + 512 * m;        // 0..4095
                int f = lin >> 4, kq = lin & 15;
                float4 v = *(const float4*)&Wfp[(size_t)f * FD + k0 + 4 * kq];
                bf16x4 p; p[0] = f2bf(v.x); p[1] = f2bf(v.y);
                          p[2] = f2bf(v.z); p[3] = f2bf(v.w);
                *(bf16x4*)&sB[f * 72 + 4 * kq] = p;
            }
        }
        __syncthreads();

        #pragma unroll
        for (int ks = 0; ks < 64; ks += 32) {
            bf16x8 af[4], bfr[2];
            #pragma unroll
            for (int it = 0; it < 4; ++it)
                af[it] = *(const bf16x8*)&sA[(16 * it + n16) * 72 + ks + quad * 8];
            #pragma unroll
            for (int fb = 0; fb < 2; ++fb)
                bfr[fb] = *(const bf16x8*)&sB[(32 * w + 16 * fb + n16) * 72 + ks + quad * 8];
            #pragma unroll
            for (int it = 0; it < 4; ++it)
                #pragma unroll
                for (int fb = 0; fb < 2; ++fb)
                    acc[it][fb] = __builtin_amdgcn_mfma_f32_16x16x32_bf16(
                        af[it], bfr[fb], acc[it][fb], 0, 0, 0);
        }
        __syncthreads();   // also protects the sB->tr reuse below
    }

    float bias[2];
    #pragma unroll
    for (int fb = 0; fb < 2; ++fb) bias[fb] = b[32 * w + 16 * fb + n16];

    if (qfp) {   // fallback path needs fp32 q
        #pragma unroll
        for (int it = 0; it < 4; ++it)
            #pragma unroll
            for (int fb = 0; fb < 2; ++fb)
                #pragma unroll
                for (int r = 0; r < 4; ++r) {
                    int i = i0 + 16 * it + 4 * quad + r;
                    int f = 32 * w + 16 * fb + n16;
                    qfp[(size_t)i * FD + f] = acc[it][fb][r] + bias[fb];
                }
    }

    if (qT) {
        // transpose to [f][i] bf16 reusing sB, then coalesced 16B stores
        short* tr = sB;
        #pragma unroll
        for (int it = 0; it < 4; ++it)
            #pragma unroll
            for (int fb = 0; fb < 2; ++fb) {
                bf16x4 p;
                #pragma unroll
                for (int r = 0; r < 4; ++r) p[r] = f2bf(acc[it][fb][r] + bias[fb]);
                int f = 32 * w + 16 * fb + n16;
                *(bf16x4*)&tr[f * 72 + 16 * it + 4 * quad] = p;
            }
        __syncthreads();
        short* qTs = qT + ((size_t)(i0 >> 9)) * FD * NA;
        const int ilb = i0 & 511;
        #pragma unroll
        for (int n = 0; n < 4; ++n) {
            int S = t + 512 * n;        // 0..2047
            int f = S >> 3;
            int c = S & 7;
            uint4 v = *(const uint4*)&tr[f * 72 + c * 8];
            *(uint4*)&qTs[(size_t)f * NA + ilb + c * 8] = v;
        }
    }
}

// ---------------------------------------------------------------------------
// Kernel 2 FAST: EXACT R6 version (best measured total, 110.2 us).
// V = 0.5 * v @ q via bf16 MFMA; out = V * q (pure store).
// Grid 512 = (s = blk&31 [XCD-local], 32 i-rows); full 256-f tile.
// Direct global->LDS staging (no register prefetch), conditional own-tile
// q snapshot, no launch_bounds occupancy cap.
// ---------------------------------------------------------------------------
__global__ __launch_bounds__(256) void lr_fast(
    const float* __restrict__ pos, float* __restrict__ out,
    const short* __restrict__ qT)
{
    __shared__ float px[NA], py[NA], pz[NA];
    __shared__ __attribute__((aligned(16))) short sqb[FD * 64];  // 32 KB
    __shared__ __attribute__((aligned(16))) short svb[32 * 64];  //  4 KB

    const int blk = blockIdx.x;
    const int s   = blk & 31;
    const int i0  = (blk >> 5) * 32;
    const int t   = threadIdx.x;
    const int w    = t >> 6;
    const int lane = t & 63;
    const int n16  = lane & 15;
    const int quad = lane >> 4;

    for (int m = t; m < NA; m += 256) {
        const float* p = &pos[((size_t)s * NA + m) * 3];
        px[m] = p[0]; py[m] = p[1]; pz[m] = p[2];
    }

    f32x4 acc[2][4];
    #pragma unroll
    for (int a = 0; a < 2; ++a)
        #pragma unroll
        for (int c = 0; c < 4; ++c) acc[a][c] = (f32x4)0.0f;
    float qreg[2][4][4];

    const short* qTs = qT + (size_t)s * FD * NA;
    const int pi = t & 31;        // pair-tile i
    const int pc = t >> 5;        // pair-tile j-chunk 0..7
    const int gi = i0 + pi;

    __syncthreads();
    const float xi = px[gi], yi = py[gi], zi = pz[gi];

    for (int j0 = 0; j0 < NA; j0 += 64) {
        // ---- stage q tile: 256f x 64j bf16, 8 x 16B chunks per thread ----
        #pragma unroll
        for (int n = 0; n < 8; ++n) {
            int S  = n * 256 + t;        // 0..2047
            int f  = S >> 3;
            int cs = S & 7;              // LDS slot
            int c  = (cs - f) & 7;       // source chunk
            uint4 v = *(const uint4*)&qTs[(size_t)f * NA + j0 + c * 8];
            *(uint4*)&sqb[f * 64 + cs * 8] = v;
        }
        // ---- v tile: 32i x 64j ----
        bf16x8 vrow;
        #pragma unroll
        for (int jj = 0; jj < 8; ++jj) {
            int gj = j0 + pc * 8 + jj;
            float dx = xi - px[gj];
            float dy = yi - py[gj];
            float dz = zi - pz[gj];
            float r2 = dx * dx + dy * dy + dz * dz;
            float inv = __builtin_amdgcn_rsqf(r2);
            float dd  = r2 * inv;
            // 1 - fcut = sin^2(pi*d/10) for d<5, else 1; 0.5 energy factor
            float sn = __sinf(dd * 0.31415926535f);
            float om = (dd < 5.0f) ? sn * sn : 1.0f;
            float vv = (gi != gj) ? 0.5f * om * inv : 0.0f;
            vrow[jj] = f2bf(vv);
        }
        *(bf16x8*)&svb[pi * 64 + (((pc + pi) & 7) * 8)] = vrow;
        __syncthreads();

        // ---- own-tile q snapshot (once; uniform branch) ----
        if (j0 == (i0 & ~63)) {
            const int jb0 = i0 & 63;     // 0 or 32
            #pragma unroll
            for (int it = 0; it < 2; ++it)
                #pragma unroll
                for (int fb = 0; fb < 4; ++fb) {
                    int f = 64 * w + 16 * fb + n16;
                    #pragma unroll
                    for (int r = 0; r < 4; ++r) {
                        int jl = jb0 + 16 * it + 4 * quad + r;
                        int c  = jl >> 3, o = jl & 7;
                        qreg[it][fb][r] =
                            bf2f(sqb[f * 64 + (((c + f) & 7) * 8) + o]);
                    }
                }
        }

        // ---- fragments + MFMA: 2 it x 4 fb x 2 kh = 16 mfma / wave ----
        bf16x8 af[2][2], bfr[2][4];
        #pragma unroll
        for (int it = 0; it < 2; ++it)
            #pragma unroll
            for (int kh = 0; kh < 2; ++kh) {
                int i = 16 * it + n16;
                int c = kh * 4 + quad;
                af[it][kh] = *(const bf16x8*)&svb[i * 64 + (((c + i) & 7) * 8)];
            }
        #pragma unroll
        for (int fb = 0; fb < 4; ++fb)
            #pragma unroll
            for (int kh = 0; kh < 2; ++kh) {
                int f = 64 * w + 16 * fb + n16;
                int c = kh * 4 + quad;
                bfr[kh][fb] = *(const bf16x8*)&sqb[f * 64 + (((c + f) & 7) * 8)];
            }
        #pragma unroll
        for (int kh = 0; kh < 2; ++kh)
            #pragma unroll
            for (int it = 0; it < 2; ++it)
                #pragma unroll
                for (int fb = 0; fb < 4; ++fb)
                    acc[it][fb] = __builtin_amdgcn_mfma_f32_16x16x32_bf16(
                        af[it][kh], bfr[kh][fb], acc[it][fb], 0, 0, 0);
        __syncthreads();
    }

    // epilogue: out = V * q  (pure store, q from registers)
    #pragma unroll
    for (int it = 0; it < 2; ++it)
        #pragma unroll
        for (int fb = 0; fb < 4; ++fb)
            #pragma unroll
            for (int r = 0; r < 4; ++r) {
                int i = i0 + 16 * it + 4 * quad + r;
                int f = 64 * w + 16 * fb + n16;
                size_t a = ((size_t)s * NA + i) * FD + f;
                out[a] = acc[it][fb][r] * qreg[it][fb][r];
            }
}

// ---------------------------------------------------------------------------
// Kernel 2 FALLBACK (cooperative, validated round 4) — used if ws too small.
// ---------------------------------------------------------------------------
__global__ __launch_bounds__(256) void lr_coop(
    const float* __restrict__ pos, float* __restrict__ gbuf)
{
    __shared__ float px[NA], py[NA], pz[NA];
    __shared__ __attribute__((aligned(16))) short svb[64 * 40];
    __shared__ __attribute__((aligned(16))) short sqb[FD * 40];

    const int blk = blockIdx.x;
    const int s   = blk & 31;
    const int i0  = (blk >> 5) * 64;
    const int t   = threadIdx.x;
    const int w    = t >> 6;
    const int lane = t & 63;
    const int n16  = lane & 15;
    const int quad = lane >> 4;

    for (int m = t; m < NA; m += 256) {
        const float* p = &pos[((size_t)s * NA + m) * 3];
        px[m] = p[0]; py[m] = p[1]; pz[m] = p[2];
    }

    f32x4 acc[4][4];
    #pragma unroll
    for (int a = 0; a < 4; ++a)
        #pragma unroll
        for (int c = 0; c < 4; ++c) acc[a][c] = (f32x4)0.0f;

    __syncthreads();

    const int fq  = t >> 2;
    const int jb  = t & 3;
    const int iv  = t & 63;
    const int jbv = t >> 6;
    const int gi  = i0 + iv;

    float4 rq[8];
    #pragma unroll
    for (int m = 0; m < 8; ++m)
        rq[m] = *(const float4*)&gbuf[((size_t)s * NA + 8 * jb + m) * FD + 4 * fq];

    for (int j0 = 0; j0 < NA; j0 += 32) {
        bf16x8 vrow;
        #pragma unroll
        for (int jj = 0; jj < 8; ++jj) {
            int gj = j0 + 8 * jbv + jj;
            float dx = px[gi] - px[gj];
            float dy = py[gi] - py[gj];
            float dz = pz[gi] - pz[gj];
            float dd = sqrtf(dx * dx + dy * dy + dz * dz);
            float om = (dd < 5.0f) ? 0.5f * (1.0f - __cosf(dd * 0.62831853071795f))
                                   : 1.0f;
            float vv = (gi != gj) ? (0.5f * om * __builtin_amdgcn_rcpf(dd)) : 0.0f;
            vrow[jj] = f2bf(vv);
        }
        bf16x8 rows[4];
        #pragma unroll
        for (int m = 0; m < 8; ++m) {
            rows[0][m] = f2bf(rq[m].x);
            rows[1][m] = f2bf(rq[m].y);
            rows[2][m] = f2bf(rq[m].z);
            rows[3][m] = f2bf(rq[m].w);
        }
        #pragma unroll
        for (int d = 0; d < 4; ++d) {
            int f = 4 * fq + d;
            int phys = (jb + (f >> 3)) & 3;
            *(bf16x8*)&sqb[f * 40 + phys * 8] = rows[d];
        }
        {
            int phys = (jbv + (iv >> 3)) & 3;
            *(bf16x8*)&svb[iv * 40 + phys * 8] = vrow;
        }
        {
            int jn = (j0 + 32) & (NA - 1);
            #pragma unroll
            for (int m = 0; m < 8; ++m)
                rq[m] = *(const float4*)&gbuf[((size_t)s * NA + jn + 8 * jb + m) * FD + 4 * fq];
        }
        __syncthreads();

        bf16x8 af[4], bfr[4];
        #pragma unroll
        for (int it = 0; it < 4; ++it) {
            int i = 16 * it + n16;
            int phys = (quad + (i >> 3)) & 3;
            af[it] = *(const bf16x8*)&svb[i * 40 + phys * 8];
        }
        #pragma unroll
        for (int fb = 0; fb < 4; ++fb) {
            int f = 16 * (4 * w + fb) + n16;
            int phys = (quad + (f >> 3)) & 3;
            bfr[fb] = *(const bf16x8*)&sqb[f * 40 + phys * 8];
        }
        #pragma unroll
        for (int it = 0; it < 4; ++it)
            #pragma unroll
            for (int fb = 0; fb < 4; ++fb)
                acc[it][fb] = __builtin_amdgcn_mfma_f32_16x16x32_bf16(
                    af[it], bfr[fb], acc[it][fb], 0, 0, 0);
        __syncthreads();
    }

    cooperative_groups::this_grid().sync();

    #pragma unroll
    for (int it = 0; it < 4; ++it)
        #pragma unroll
        for (int fb = 0; fb < 4; ++fb)
            #pragma unroll
            for (int r = 0; r < 4; ++r) {
                int i = i0 + 16 * it + 4 * quad + r;
                int f = 16 * (4 * w + fb) + n16;
                size_t a = ((size_t)s * NA + i) * FD + f;
                gbuf[a] = acc[it][fb][r] * gbuf[a];
            }
}

extern "C" void kernel_launch(void* const* d_in, const int* in_sizes, int n_in,
                              void* d_out, int out_size, void* d_ws, size_t ws_size,
                              hipStream_t stream) {
    const float* positions = (const float*)d_in[0];  // [32,512,3]
    const float* features  = (const float*)d_in[1];  // [16384,256]
    const float* W         = (const float*)d_in[2];  // [256,256]
    const float* b         = (const float*)d_in[3];  // [256]
    float* gbuf = (float*)d_out;

    const size_t qT_elems = (size_t)SY * NA * FD;              // 4M bf16
    const size_t need = (qT_elems + FD * FD) * sizeof(short);  // 8 MB + 128 KB
    const bool fast = (ws_size >= need);

    if (fast) {
        short* qT = (short*)d_ws;
        short* Wb = (short*)d_ws + qT_elems;
        prep_w<<<dim3(64), 256, 0, stream>>>(W, Wb);
        charges_v25<<<dim3(256), 512, 0, stream>>>(features, W, Wb, b, nullptr, qT);
        lr_fast<<<dim3(512), 256, 0, stream>>>(positions, gbuf, qT);
    } else {
        charges_v25<<<dim3(256), 512, 0, stream>>>(features, W, nullptr, b, gbuf, nullptr);
        void* args[] = {(void*)&positions, (void*)&gbuf};
        hipLaunchCooperativeKernel((void*)lr_coop, dim3(256), dim3(256),
                                   args, 0, stream);
    }
}

// Round 11
// 110.989 us; speedup vs baseline: 1.1576x; 1.0163x over previous
//
#include <hip/hip_runtime.h>
#include <hip/hip_cooperative_groups.h>

// S=32 systems, N=512 atoms/system, F=256 features
#define SY 32
#define NA 512
#define FD 256

typedef __attribute__((ext_vector_type(8))) short bf16x8;   // 8 bf16 = 4 VGPRs
typedef __attribute__((ext_vector_type(4))) short bf16x4;   // 4 bf16 = 8 B
typedef __attribute__((ext_vector_type(4))) float f32x4;    // MFMA C/D frag

static __device__ __forceinline__ short f2bf(float x) {
    union { float f; unsigned u; } v; v.f = x;
    unsigned r = v.u + 0x7fffu + ((v.u >> 16) & 1u);   // RNE
    return (short)(r >> 16);
}
static __device__ __forceinline__ float bf2f(short x) {
    union { float f; unsigned u; } v;
    v.u = ((unsigned)(unsigned short)x) << 16;
    return v.f;
}

// ---------------------------------------------------------------------------
// prep: W fp32 -> bf16 (row-major [f][k] unchanged). 64 blocks x 256 thr.
// ---------------------------------------------------------------------------
__global__ __launch_bounds__(256) void prep_w(
    const float* __restrict__ W, short* __restrict__ Wb)
{
    int idx = (blockIdx.x * 256 + threadIdx.x) * 4;   // 65536 elems total
    float4 v = *(const float4*)&W[idx];
    bf16x4 p; p[0] = f2bf(v.x); p[1] = f2bf(v.y);
              p[2] = f2bf(v.z); p[3] = f2bf(v.w);
    *(bf16x4*)&Wb[idx] = p;
}

// ---------------------------------------------------------------------------
// Kernel 1 (unchanged from R10): charges via bf16 MFMA (fp32 accum).
// 256 blocks x 512 thr, 64 i-rows x 256 f; wave w owns f in [32w,32w+32).
// ---------------------------------------------------------------------------
__global__ __launch_bounds__(512) void charges_v25(
    const float* __restrict__ feat, const float* __restrict__ Wfp,
    const short* __restrict__ Wb, const float* __restrict__ b,
    float* __restrict__ qfp, short* __restrict__ qT)
{
    __shared__ __attribute__((aligned(16))) short sA[64 * 72];   //  9.2 KB
    __shared__ __attribute__((aligned(16))) short sB[256 * 72];  // 36.9 KB
    const int t    = threadIdx.x;
    const int i0   = blockIdx.x * 64;
    const int w    = t >> 6;            // wave 0..7
    const int lane = t & 63;
    const int n16  = lane & 15;
    const int quad = lane >> 4;

    f32x4 acc[4][2];
    #pragma unroll
    for (int a = 0; a < 4; ++a)
        #pragma unroll
        for (int c = 0; c < 2; ++c) acc[a][c] = (f32x4)0.0f;

    for (int k0 = 0; k0 < FD; k0 += 64) {
        #pragma unroll
        for (int m = 0; m < 2; ++m) {
            int lin = t + 512 * m;            // 0..1023
            int row = lin >> 4, kq = lin & 15;
            float4 v = *(const float4*)&feat[(size_t)(i0 + row) * FD + k0 + 4 * kq];
            bf16x4 p; p[0] = f2bf(v.x); p[1] = f2bf(v.y);
                      p[2] = f2bf(v.z); p[3] = f2bf(v.w);
            *(bf16x4*)&sA[row * 72 + 4 * kq] = p;
        }
        if (Wb) {
            #pragma unroll
            for (int n = 0; n < 4; ++n) {
                int S = t + 512 * n;          // 0..2047 16B chunks
                int f = S >> 3, c = S & 7;
                uint4 v = *(const uint4*)&Wb[(size_t)f * FD + k0 + c * 8];
                *(uint4*)&sB[f * 72 + c * 8] = v;
            }
        } else {
            #pragma unroll
            for (int m = 0; m < 8; ++m) {
                int lin = t + 512 * m;        // 0..4095
                int f = lin >> 4, kq = lin & 15;
                float4 v = *(const float4*)&Wfp[(size_t)f * FD + k0 + 4 * kq];
                bf16x4 p; p[0] = f2bf(v.x); p[1] = f2bf(v.y);
                          p[2] = f2bf(v.z); p[3] = f2bf(v.w);
                *(bf16x4*)&sB[f * 72 + 4 * kq] = p;
            }
        }
        __syncthreads();

        #pragma unroll
        for (int ks = 0; ks < 64; ks += 32) {
            bf16x8 af[4], bfr[2];
            #pragma unroll
            for (int it = 0; it < 4; ++it)
                af[it] = *(const bf16x8*)&sA[(16 * it + n16) * 72 + ks + quad * 8];
            #pragma unroll
            for (int fb = 0; fb < 2; ++fb)
                bfr[fb] = *(const bf16x8*)&sB[(32 * w + 16 * fb + n16) * 72 + ks + quad * 8];
            #pragma unroll
            for (int it = 0; it < 4; ++it)
                #pragma unroll
                for (int fb = 0; fb < 2; ++fb)
                    acc[it][fb] = __builtin_amdgcn_mfma_f32_16x16x32_bf16(
                        af[it], bfr[fb], acc[it][fb], 0, 0, 0);
        }
        __syncthreads();   // also protects the sB->tr reuse below
    }

    float bias[2];
    #pragma unroll
    for (int fb = 0; fb < 2; ++fb) bias[fb] = b[32 * w + 16 * fb + n16];

    if (qfp) {
        #pragma unroll
        for (int it = 0; it < 4; ++it)
            #pragma unroll
            for (int fb = 0; fb < 2; ++fb)
                #pragma unroll
                for (int r = 0; r < 4; ++r) {
                    int i = i0 + 16 * it + 4 * quad + r;
                    int f = 32 * w + 16 * fb + n16;
                    qfp[(size_t)i * FD + f] = acc[it][fb][r] + bias[fb];
                }
    }

    if (qT) {
        short* tr = sB;
        #pragma unroll
        for (int it = 0; it < 4; ++it)
            #pragma unroll
            for (int fb = 0; fb < 2; ++fb) {
                bf16x4 p;
                #pragma unroll
                for (int r = 0; r < 4; ++r) p[r] = f2bf(acc[it][fb][r] + bias[fb]);
                int f = 32 * w + 16 * fb + n16;
                *(bf16x4*)&tr[f * 72 + 16 * it + 4 * quad] = p;
            }
        __syncthreads();
        short* qTs = qT + ((size_t)(i0 >> 9)) * FD * NA;
        const int ilb = i0 & 511;
        #pragma unroll
        for (int n = 0; n < 4; ++n) {
            int S = t + 512 * n;        // 0..2047
            int f = S >> 3;
            int c = S & 7;
            uint4 v = *(const uint4*)&tr[f * 72 + c * 8];
            *(uint4*)&qTs[(size_t)f * NA + ilb + c * 8] = v;
        }
    }
}

// ---------------------------------------------------------------------------
// Kernel 2 FAST v5 (R11): whole-system q resident in LDS.
// Grid 512 = (s = blk&31 [XCD-local], rr = blk>>5: fh = rr&1 -> 128-f half,
// ic = rr>>1 -> 64 i-rows). Stage qT[s][f-half][ALL 512 j] = 128 KB in LDS
// ONCE; j-loop then has ZERO global loads: pair VALU -> svb -> barrier ->
// LDS frags -> 16 MFMA/wave -> barrier. LDS 142 KB -> 1 block/CU.
// sqb swizzle: 16B chunk c of row fl stored at slot (c+fl)&63 ->
// conflict-free staging, <=2-way (free) frag reads.
// ---------------------------------------------------------------------------
__global__ __launch_bounds__(256) void lr_fast(
    const float* __restrict__ pos, float* __restrict__ out,
    const short* __restrict__ qT)
{
    __shared__ float px[NA], py[NA], pz[NA];                      //  6 KB
    __shared__ __attribute__((aligned(16))) short sqb[128 * NA];  // 128 KB
    __shared__ __attribute__((aligned(16))) short svb[64 * 64];   //   8 KB

    const int blk = blockIdx.x;
    const int s   = blk & 31;
    const int rr  = blk >> 5;
    const int f0  = (rr & 1) * 128;
    const int i0  = (rr >> 1) * 64;
    const int t   = threadIdx.x;
    const int w    = t >> 6;
    const int lane = t & 63;
    const int n16  = lane & 15;
    const int quad = lane >> 4;

    for (int m = t; m < NA; m += 256) {
        const float* p = &pos[((size_t)s * NA + m) * 3];
        px[m] = p[0]; py[m] = p[1]; pz[m] = p[2];
    }

    f32x4 acc[4][2];
    #pragma unroll
    for (int a = 0; a < 4; ++a)
        #pragma unroll
        for (int c = 0; c < 2; ++c) acc[a][c] = (f32x4)0.0f;

    const short* qTs = qT + (size_t)s * FD * NA + (size_t)f0 * NA;

    // ---- stage q f-half: 128 rows x 512 j bf16 = 8192 16B chunks ----
    #pragma unroll
    for (int g = 0; g < 4; ++g) {
        uint4 v[8];
        #pragma unroll
        for (int n = 0; n < 8; ++n) {
            int S  = t + 256 * (8 * g + n);   // 0..8191
            int fl = S >> 6;
            int cs = S & 63;
            int c  = (cs - fl) & 63;
            v[n] = *(const uint4*)&qTs[(size_t)fl * NA + c * 8];
        }
        #pragma unroll
        for (int n = 0; n < 8; ++n) {
            int S  = t + 256 * (8 * g + n);
            int fl = S >> 6;
            int cs = S & 63;
            *(uint4*)&sqb[fl * NA + cs * 8] = v[n];
        }
    }

    const int pi  = t & 63;       // pair i (0..63)
    const int pjc = t >> 6;       // pair j-sub (0..3), 16 j each
    const int gi  = i0 + pi;

    __syncthreads();
    const float xi = px[gi], yi = py[gi], zi = pz[gi];

    for (int j0 = 0; j0 < NA; j0 += 64) {
        // ---- v tile: 64i x 64j (16 pairs/thread) ----
        #pragma unroll
        for (int h = 0; h < 2; ++h) {
            bf16x8 vr;
            #pragma unroll
            for (int jj = 0; jj < 8; ++jj) {
                int gj = j0 + pjc * 16 + h * 8 + jj;
                float dx = xi - px[gj];
                float dy = yi - py[gj];
                float dz = zi - pz[gj];
                float r2 = dx * dx + dy * dy + dz * dz;
                float inv = __builtin_amdgcn_rsqf(r2);
                float dd  = r2 * inv;
                // 1 - fcut = sin^2(pi*d/10) for d<5, else 1; 0.5 energy factor
                float sn = __sinf(dd * 0.31415926535f);
                float om = (dd < 5.0f) ? sn * sn : 1.0f;
                float vv = (gi != gj) ? 0.5f * om * inv : 0.0f;
                vr[jj] = f2bf(vv);
            }
            int c = pjc * 2 + h;
            *(bf16x8*)&svb[pi * 64 + (((c + pi) & 7) * 8)] = vr;
        }
        __syncthreads();

        // ---- fragments + MFMA: 4 it x 2 fb x 2 kh = 16 mfma / wave ----
        bf16x8 af[4][2], bfr[2][2];
        #pragma unroll
        for (int it = 0; it < 4; ++it)
            #pragma unroll
            for (int kh = 0; kh < 2; ++kh) {
                int i = 16 * it + n16;
                int c = kh * 4 + quad;
                af[it][kh] = *(const bf16x8*)&svb[i * 64 + (((c + i) & 7) * 8)];
            }
        const int jc0 = j0 >> 3;
        #pragma unroll
        for (int fb = 0; fb < 2; ++fb)
            #pragma unroll
            for (int kh = 0; kh < 2; ++kh) {
                int fl = 32 * w + 16 * fb + n16;
                int cg = jc0 + kh * 4 + quad;
                bfr[kh][fb] = *(const bf16x8*)&sqb[fl * NA + (((cg + fl) & 63) * 8)];
            }
        #pragma unroll
        for (int kh = 0; kh < 2; ++kh)
            #pragma unroll
            for (int it = 0; it < 4; ++it)
                #pragma unroll
                for (int fb = 0; fb < 2; ++fb)
                    acc[it][fb] = __builtin_amdgcn_mfma_f32_16x16x32_bf16(
                        af[it][kh], bfr[kh][fb], acc[it][fb], 0, 0, 0);
        __syncthreads();
    }

    // epilogue: out = V * q (q loaded here -> short live range, no spills)
    #pragma unroll
    for (int it = 0; it < 4; ++it)
        #pragma unroll
        for (int fb = 0; fb < 2; ++fb) {
            int fl = 32 * w + 16 * fb + n16;
            bf16x4 p = *(const bf16x4*)&qTs[(size_t)fl * NA + i0 + 16 * it + 4 * quad];
            #pragma unroll
            for (int r = 0; r < 4; ++r) {
                int i = i0 + 16 * it + 4 * quad + r;
                size_t a = ((size_t)s * NA + i) * FD + f0 + fl;
                out[a] = acc[it][fb][r] * bf2f(p[r]);
            }
        }
}

// ---------------------------------------------------------------------------
// Kernel 2 FALLBACK (cooperative, validated round 4) — used if ws too small.
// ---------------------------------------------------------------------------
__global__ __launch_bounds__(256) void lr_coop(
    const float* __restrict__ pos, float* __restrict__ gbuf)
{
    __shared__ float px[NA], py[NA], pz[NA];
    __shared__ __attribute__((aligned(16))) short svb[64 * 40];
    __shared__ __attribute__((aligned(16))) short sqb[FD * 40];

    const int blk = blockIdx.x;
    const int s   = blk & 31;
    const int i0  = (blk >> 5) * 64;
    const int t   = threadIdx.x;
    const int w    = t >> 6;
    const int lane = t & 63;
    const int n16  = lane & 15;
    const int quad = lane >> 4;

    for (int m = t; m < NA; m += 256) {
        const float* p = &pos[((size_t)s * NA + m) * 3];
        px[m] = p[0]; py[m] = p[1]; pz[m] = p[2];
    }

    f32x4 acc[4][4];
    #pragma unroll
    for (int a = 0; a < 4; ++a)
        #pragma unroll
        for (int c = 0; c < 4; ++c) acc[a][c] = (f32x4)0.0f;

    __syncthreads();

    const int fq  = t >> 2;
    const int jb  = t & 3;
    const int iv  = t & 63;
    const int jbv = t >> 6;
    const int gi  = i0 + iv;

    float4 rq[8];
    #pragma unroll
    for (int m = 0; m < 8; ++m)
        rq[m] = *(const float4*)&gbuf[((size_t)s * NA + 8 * jb + m) * FD + 4 * fq];

    for (int j0 = 0; j0 < NA; j0 += 32) {
        bf16x8 vrow;
        #pragma unroll
        for (int jj = 0; jj < 8; ++jj) {
            int gj = j0 + 8 * jbv + jj;
            float dx = px[gi] - px[gj];
            float dy = py[gi] - py[gj];
            float dz = pz[gi] - pz[gj];
            float dd = sqrtf(dx * dx + dy * dy + dz * dz);
            float om = (dd < 5.0f) ? 0.5f * (1.0f - __cosf(dd * 0.62831853071795f))
                                   : 1.0f;
            float vv = (gi != gj) ? (0.5f * om * __builtin_amdgcn_rcpf(dd)) : 0.0f;
            vrow[jj] = f2bf(vv);
        }
        bf16x8 rows[4];
        #pragma unroll
        for (int m = 0; m < 8; ++m) {
            rows[0][m] = f2bf(rq[m].x);
            rows[1][m] = f2bf(rq[m].y);
            rows[2][m] = f2bf(rq[m].z);
            rows[3][m] = f2bf(rq[m].w);
        }
        #pragma unroll
        for (int d = 0; d < 4; ++d) {
            int f = 4 * fq + d;
            int phys = (jb + (f >> 3)) & 3;
            *(bf16x8*)&sqb[f * 40 + phys * 8] = rows[d];
        }
        {
            int phys = (jbv + (iv >> 3)) & 3;
            *(bf16x8*)&svb[iv * 40 + phys * 8] = vrow;
        }
        {
            int jn = (j0 + 32) & (NA - 1);
            #pragma unroll
            for (int m = 0; m < 8; ++m)
                rq[m] = *(const float4*)&gbuf[((size_t)s * NA + jn + 8 * jb + m) * FD + 4 * fq];
        }
        __syncthreads();

        bf16x8 af[4], bfr[4];
        #pragma unroll
        for (int it = 0; it < 4; ++it) {
            int i = 16 * it + n16;
            int phys = (quad + (i >> 3)) & 3;
            af[it] = *(const bf16x8*)&svb[i * 40 + phys * 8];
        }
        #pragma unroll
        for (int fb = 0; fb < 4; ++fb) {
            int f = 16 * (4 * w + fb) + n16;
            int phys = (quad + (f >> 3)) & 3;
            bfr[fb] = *(const bf16x8*)&sqb[f * 40 + phys * 8];
        }
        #pragma unroll
        for (int it = 0; it < 4; ++it)
            #pragma unroll
            for (int fb = 0; fb < 4; ++fb)
                acc[it][fb] = __builtin_amdgcn_mfma_f32_16x16x32_bf16(
                    af[it], bfr[fb], acc[it][fb], 0, 0, 0);
        __syncthreads();
    }

    cooperative_groups::this_grid().sync();

    #pragma unroll
    for (int it = 0; it < 4; ++it)
        #pragma unroll
        for (int fb = 0; fb < 4; ++fb)
            #pragma unroll
            for (int r = 0; r < 4; ++r) {
                int i = i0 + 16 * it + 4 * quad + r;
                int f = 16 * (4 * w + fb) + n16;
                size_t a = ((size_t)s * NA + i) * FD + f;
                gbuf[a] = acc[it][fb][r] * gbuf[a];
            }
}

extern "C" void kernel_launch(void* const* d_in, const int* in_sizes, int n_in,
                              void* d_out, int out_size, void* d_ws, size_t ws_size,
                              hipStream_t stream) {
    const float* positions = (const float*)d_in[0];  // [32,512,3]
    const float* features  = (const float*)d_in[1];  // [16384,256]
    const float* W         = (const float*)d_in[2];  // [256,256]
    const float* b         = (const float*)d_in[3];  // [256]
    float* gbuf = (float*)d_out;

    const size_t qT_elems = (size_t)SY * NA * FD;              // 4M bf16
    const size_t need = (qT_elems + FD * FD) * sizeof(short);  // 8 MB + 128 KB
    const bool fast = (ws_size >= need);

    if (fast) {
        short* qT = (short*)d_ws;
        short* Wb = (short*)d_ws + qT_elems;
        prep_w<<<dim3(64), 256, 0, stream>>>(W, Wb);
        charges_v25<<<dim3(256), 512, 0, stream>>>(features, W, Wb, b, nullptr, qT);
        lr_fast<<<dim3(512), 256, 0, stream>>>(positions, gbuf, qT);
    } else {
        charges_v25<<<dim3(256), 512, 0, stream>>>(features, W, nullptr, b, gbuf, nullptr);
        void* args[] = {(void*)&positions, (void*)&gbuf};
        hipLaunchCooperativeKernel((void*)lr_coop, dim3(256), dim3(256),
                                   args, 0, stream);
    }
}